// Round 1
// baseline (356.414 us; speedup 1.0000x reference)
//
#include <hip/hip_runtime.h>
#include <math.h>

#define N_LM 543
#define ROW (N_LM * 3)          // 1629 floats per row (6516 B, NOT 16B-aligned)
#define RPB 4                   // rows per block: 4*6516 B = 26064 B, 16B-aligned
#define CHUNKS (RPB * N_LM / 4) // 543 twelve-float (4-landmark) chunks per block
#define L_SH 11
#define R_SH 12

__global__ __launch_bounds__(256)
void sim3_kernel(const float* __restrict__ in, float* __restrict__ out, int T) {
    __shared__ float P[RPB][8];   // c, st, inv_s, nx, ny, nz per row
    const int b = blockIdx.x;
    const int row0 = b * RPB;

    // --- per-row params: 4 threads, one row each ---
    if (threadIdx.x < RPB) {
        const int t = row0 + threadIdx.x;
        if (t < T) {
            const float* __restrict__ row = in + (size_t)t * ROW;
            const float nx = row[0], ny = row[1], nz = row[2];
            const float lsx = row[L_SH * 3 + 0], lsy = row[L_SH * 3 + 1], lsz = row[L_SH * 3 + 2];
            const float rsx = row[R_SH * 3 + 0], rsy = row[R_SH * 3 + 1], rsz = row[R_SH * 3 + 2];

            const float svx = rsx - lsx;
            const float svy = rsy - lsy;
            const float svz = rsz - lsz;

            const float s = sqrtf(svx * svx + svy * svy + svz * svz) + 1e-8f;
            const float inv_s = 1.0f / s;

            const float sxz_n = sqrtf(svx * svx + svz * svz) + 1e-8f;
            float c = svx / sxz_n;
            c = fminf(fmaxf(c, -1.0f), 1.0f);
            float st = sqrtf(fmaxf(1.0f - c * c, 0.0f));
            if (fabsf(c) > 0.9999f) { c = 1.0f; st = 0.0f; }

            P[threadIdx.x][0] = c;
            P[threadIdx.x][1] = st;
            P[threadIdx.x][2] = inv_s;
            P[threadIdx.x][3] = nx;
            P[threadIdx.x][4] = ny;
            P[threadIdx.x][5] = nz;
        }
    }
    __syncthreads();

    if (row0 + RPB <= T) {
        // --- fast path: 4 full rows, 16B-aligned span of 1629 float4s ---
        const float4* __restrict__ src = (const float4*)(in + (size_t)row0 * ROW);
        float4*       __restrict__ dst = (float4*)(out + (size_t)row0 * ROW);

        for (int ch = threadIdx.x; ch < CHUNKS; ch += 256) {
            const float4 v0 = src[ch * 3 + 0];
            const float4 v1 = src[ch * 3 + 1];
            const float4 v2 = src[ch * 3 + 2];

            // chunk = 4 consecutive landmarks, landmark-aligned (12 floats)
            const float xin[4] = { v0.x, v0.w, v1.z, v2.y };
            const float yin[4] = { v0.y, v1.x, v1.w, v2.z };
            const float zin[4] = { v0.z, v1.y, v2.x, v2.w };
            float o[12];

            const int l0 = ch * 4;  // local landmark index of first of the 4
            #pragma unroll
            for (int m = 0; m < 4; ++m) {
                const int l = l0 + m;
                // local row within the 4-row span: 3 compares, no division
                const int r = (l >= N_LM) + (l >= 2 * N_LM) + (l >= 3 * N_LM);
                const float c  = P[r][0];
                const float st = P[r][1];
                const float is = P[r][2];
                const float x = xin[m] - P[r][3];
                const float y = yin[m] - P[r][4];
                const float z = zin[m] - P[r][5];
                o[m * 3 + 0] = (c * x + st * z) * is;
                o[m * 3 + 1] = y * is;
                o[m * 3 + 2] = (c * z - st * x) * is;
            }

            dst[ch * 3 + 0] = make_float4(o[0], o[1],  o[2],  o[3]);
            dst[ch * 3 + 1] = make_float4(o[4], o[5],  o[6],  o[7]);
            dst[ch * 3 + 2] = make_float4(o[8], o[9],  o[10], o[11]);
        }
    } else {
        // --- tail path (T not divisible by RPB): scalar, same math ---
        for (int rr = 0; rr < RPB; ++rr) {
            const int t = row0 + rr;
            if (t >= T) break;
            const float* __restrict__ row  = in  + (size_t)t * ROW;
            float*       __restrict__ orow = out + (size_t)t * ROW;
            const float c  = P[rr][0], st = P[rr][1], is = P[rr][2];
            const float nx = P[rr][3], ny = P[rr][4], nz = P[rr][5];
            for (int n = threadIdx.x; n < N_LM; n += 256) {
                const int o = n * 3;
                const float x = row[o + 0] - nx;
                const float y = row[o + 1] - ny;
                const float z = row[o + 2] - nz;
                orow[o + 0] = (c * x + st * z) * is;
                orow[o + 1] = y * is;
                orow[o + 2] = (c * z - st * x) * is;
            }
        }
    }
}

extern "C" void kernel_launch(void* const* d_in, const int* in_sizes, int n_in,
                              void* d_out, int out_size, void* d_ws, size_t ws_size,
                              hipStream_t stream) {
    const float* in = (const float*)d_in[0];
    float* out = (float*)d_out;
    const int T = in_sizes[0] / ROW;          // 32768
    const int grid = (T + RPB - 1) / RPB;     // 8192 blocks
    sim3_kernel<<<grid, 256, 0, stream>>>(in, out, T);
}

// Round 2
// 354.589 us; speedup vs baseline: 1.0051x; 1.0051x over previous
//
#include <hip/hip_runtime.h>
#include <math.h>

#define N_LM 543
#define ROW (N_LM * 3)              // 1629 floats per row (6516 B)
#define RPB 4                       // 4 rows/group: 26064 B, 16B-aligned
#define GRP_FLOATS (RPB * ROW)      // 6516 floats
#define GRP_VEC4  (GRP_FLOATS / 4)  // 1629 float4s per group
#define GRP_LM    (RPB * N_LM)      // 2172 landmarks per group
#define NTHREADS 256
#define L_SH 11
#define R_SH 12

__global__ __launch_bounds__(NTHREADS)
void sim3_kernel(const float* __restrict__ in, float* __restrict__ out, int T) {
    __shared__ float4 buf4[GRP_VEC4];   // 26064 B staging buffer
    __shared__ float  P[RPB][8];        // c, st, inv_s, nx, ny, nz per row
    float* buf = (float*)buf4;

    const int row0 = blockIdx.x * RPB;

    if (row0 + RPB <= T) {
        // ---- per-row params from global (uniform scalar loads, 4 threads) ----
        if (threadIdx.x < RPB) {
            const float* __restrict__ row = in + (size_t)(row0 + threadIdx.x) * ROW;
            const float nx = row[0], ny = row[1], nz = row[2];
            const float lsx = row[L_SH * 3 + 0], lsy = row[L_SH * 3 + 1], lsz = row[L_SH * 3 + 2];
            const float rsx = row[R_SH * 3 + 0], rsy = row[R_SH * 3 + 1], rsz = row[R_SH * 3 + 2];

            const float svx = rsx - lsx;
            const float svy = rsy - lsy;
            const float svz = rsz - lsz;

            const float s = sqrtf(svx * svx + svy * svy + svz * svz) + 1e-8f;
            const float inv_s = 1.0f / s;

            const float sxz_n = sqrtf(svx * svx + svz * svz) + 1e-8f;
            float c = svx / sxz_n;
            c = fminf(fmaxf(c, -1.0f), 1.0f);
            float st = sqrtf(fmaxf(1.0f - c * c, 0.0f));
            if (fabsf(c) > 0.9999f) { c = 1.0f; st = 0.0f; }

            P[threadIdx.x][0] = c;
            P[threadIdx.x][1] = st;
            P[threadIdx.x][2] = inv_s;
            P[threadIdx.x][3] = nx;
            P[threadIdx.x][4] = ny;
            P[threadIdx.x][5] = nz;
        }

        // ---- phase 1: copy-pattern load, lane-stride 16B contiguous ----
        const float4* __restrict__ src = (const float4*)(in + (size_t)row0 * ROW);
        for (int i = threadIdx.x; i < GRP_VEC4; i += NTHREADS)
            buf4[i] = src[i];
        __syncthreads();

        // ---- phase 2: in-place per-landmark rotate in LDS ----
        // lane-stride 3 floats -> bank stride 3 (coprime with 32): 2-way max, free
        for (int l = threadIdx.x; l < GRP_LM; l += NTHREADS) {
            const int r = (l >= N_LM) + (l >= 2 * N_LM) + (l >= 3 * N_LM);
            const float c  = P[r][0];
            const float st = P[r][1];
            const float is = P[r][2];
            const int o = l * 3;
            const float x = buf[o + 0] - P[r][3];
            const float y = buf[o + 1] - P[r][4];
            const float z = buf[o + 2] - P[r][5];
            buf[o + 0] = (c * x + st * z) * is;
            buf[o + 1] = y * is;
            buf[o + 2] = (c * z - st * x) * is;
        }
        __syncthreads();

        // ---- phase 3: copy-pattern store ----
        float4* __restrict__ dst = (float4*)(out + (size_t)row0 * ROW);
        for (int i = threadIdx.x; i < GRP_VEC4; i += NTHREADS)
            dst[i] = buf4[i];
    } else {
        // ---- tail path (T % RPB != 0): scalar, same math, straight from global ----
        for (int rr = 0; rr < RPB; ++rr) {
            const int t = row0 + rr;
            if (t >= T) break;
            const float* __restrict__ row  = in  + (size_t)t * ROW;
            float*       __restrict__ orow = out + (size_t)t * ROW;

            const float nx = row[0], ny = row[1], nz = row[2];
            const float lsx = row[L_SH * 3 + 0], lsy = row[L_SH * 3 + 1], lsz = row[L_SH * 3 + 2];
            const float rsx = row[R_SH * 3 + 0], rsy = row[R_SH * 3 + 1], rsz = row[R_SH * 3 + 2];
            const float svx = rsx - lsx, svy = rsy - lsy, svz = rsz - lsz;
            const float s = sqrtf(svx * svx + svy * svy + svz * svz) + 1e-8f;
            const float is = 1.0f / s;
            const float sxz_n = sqrtf(svx * svx + svz * svz) + 1e-8f;
            float c = svx / sxz_n;
            c = fminf(fmaxf(c, -1.0f), 1.0f);
            float st = sqrtf(fmaxf(1.0f - c * c, 0.0f));
            if (fabsf(c) > 0.9999f) { c = 1.0f; st = 0.0f; }

            for (int n = threadIdx.x; n < N_LM; n += NTHREADS) {
                const int o = n * 3;
                const float x = row[o + 0] - nx;
                const float y = row[o + 1] - ny;
                const float z = row[o + 2] - nz;
                orow[o + 0] = (c * x + st * z) * is;
                orow[o + 1] = y * is;
                orow[o + 2] = (c * z - st * x) * is;
            }
        }
    }
}

extern "C" void kernel_launch(void* const* d_in, const int* in_sizes, int n_in,
                              void* d_out, int out_size, void* d_ws, size_t ws_size,
                              hipStream_t stream) {
    const float* in = (const float*)d_in[0];
    float* out = (float*)d_out;
    const int T = in_sizes[0] / ROW;          // 32768
    const int grid = (T + RPB - 1) / RPB;     // 8192 blocks
    sim3_kernel<<<grid, NTHREADS, 0, stream>>>(in, out, T);
}